// Round 3
// baseline (646.589 us; speedup 1.0000x reference)
//
#include <hip/hip_runtime.h>
#include <hip/hip_bf16.h>

#define BATCH 8
#define NC 2048
#define NF 8192
#define CDIM 256
#define CSKIP 64
#define OUTD 256
#define MTOT (BATCH*NF)   // 65536
#define NCTOT (BATCH*NC)  // 16384
#define NCHUNK 8          // kNN coarse-scan split
#define CHSZ (NC/NCHUNK)  // 256

typedef __attribute__((ext_vector_type(8))) short short8;
typedef __attribute__((ext_vector_type(4))) float floatx4;

static __device__ __forceinline__ ushort f2bf(float f) {
    union { float f; unsigned u; } v; v.f = f;
    unsigned r = v.u + 0x7fffu + ((v.u >> 16) & 1u);   // RNE
    return (ushort)(r >> 16);
}

// strict-< top-3 insert (matches jax top_k stability when fed in ascending-index order)
static __device__ __forceinline__ void top3_insert(float d, int j,
                                                   float& d0, float& d1, float& d2,
                                                   int& i0, int& i1, int& i2) {
    if (d < d2) {
        if (d < d1) {
            d2 = d1; i2 = i1;
            if (d < d0) { d1 = d0; i1 = i0; d0 = d; i0 = j; }
            else        { d1 = d;  i1 = j; }
        } else { d2 = d; i2 = j; }
    }
}

// ---- kernel 1: prep (bf16 casts, weight transposes, pos padding)
#define SEG0 1048576
#define SEG1 1048576
#define SEG2 65536
#define SEG3 16384
#define SEG4 65536
#define SEG5 16384
#define PREP_THREADS (SEG0+SEG1+SEG2+SEG3+SEG4+SEG5)

__global__ __launch_bounds__(256) void prep_kernel(const float* __restrict__ x,
                                                   const float* __restrict__ x_skip,
                                                   const float* __restrict__ W1,
                                                   const float* __restrict__ W2,
                                                   const float* __restrict__ pos,
                                                   ushort* __restrict__ xb,
                                                   ushort* __restrict__ xsb,
                                                   ushort* __restrict__ Bt1a,
                                                   ushort* __restrict__ Bt1b,
                                                   ushort* __restrict__ Bt2,
                                                   float4* __restrict__ pos4) {
    int t = blockIdx.x * 256 + threadIdx.x;
    if (t < SEG0) {
        float4 v = ((const float4*)x)[t];
        ushort4 p; p.x = f2bf(v.x); p.y = f2bf(v.y); p.z = f2bf(v.z); p.w = f2bf(v.w);
        ((ushort4*)xb)[t] = p;
        return;
    }
    t -= SEG0;
    if (t < SEG1) {
        float4 v = ((const float4*)x_skip)[t];
        ushort4 p; p.x = f2bf(v.x); p.y = f2bf(v.y); p.z = f2bf(v.z); p.w = f2bf(v.w);
        ((ushort4*)xsb)[t] = p;
        return;
    }
    t -= SEG1;
    if (t < SEG2) {
        int k = t & 255, n = t >> 8;
        Bt1a[n * 256 + k] = f2bf(W1[k * 256 + n]);
        return;
    }
    t -= SEG2;
    if (t < SEG3) {
        int k2 = t & 63, n = t >> 6;
        Bt1b[n * 64 + k2] = f2bf(W1[(256 + k2) * 256 + n]);
        return;
    }
    t -= SEG3;
    if (t < SEG4) {
        int k = t & 255, n = t >> 8;
        Bt2[n * 256 + k] = f2bf(W2[k * 256 + n]);
        return;
    }
    t -= SEG4;
    if (t < SEG5) {
        float4 q;
        q.x = pos[t * 3 + 0]; q.y = pos[t * 3 + 1]; q.z = pos[t * 3 + 2]; q.w = 0.f;
        pos4[t] = q;
    }
}

// ---- kernel 2a: chunked kNN partials. Block = (m-group, chunk); 8x the waves of
// the round-2 version (which sat at 11.8% occupancy / 255 us, pure latency-bound).
__global__ __launch_bounds__(256) void knn_part(const float4* __restrict__ pos4,
                                                const float* __restrict__ pos_skip,
                                                int* __restrict__ pidx,
                                                float* __restrict__ pdst) {
    int c = blockIdx.x & (NCHUNK - 1);
    int m = (blockIdx.x >> 3) * 256 + threadIdx.x;
    int b = m >> 13;                                   // NF = 8192
    const float4* pc = pos4 + b * NC + c * CHSZ;
    int jbase = b * NC + c * CHSZ;

    float px = pos_skip[m * 3 + 0];
    float py = pos_skip[m * 3 + 1];
    float pz = pos_skip[m * 3 + 2];

    float d0 = 1e30f, d1 = 1e30f, d2 = 1e30f;
    int i0 = jbase, i1 = jbase, i2 = jbase;
#pragma unroll 4
    for (int j = 0; j < CHSZ; ++j) {
        float4 q = pc[j];
        float dx = px - q.x, dy = py - q.y, dz = pz - q.z;
        float d = dx * dx + dy * dy + dz * dz;
        top3_insert(d, jbase + j, d0, d1, d2, i0, i1, i2);
    }
    size_t base = ((size_t)c * MTOT + m) * 3;
    pdst[base + 0] = d0; pdst[base + 1] = d1; pdst[base + 2] = d2;
    pidx[base + 0] = i0; pidx[base + 1] = i1; pidx[base + 2] = i2;
}

// ---- kernel 2b: merge 8 chunk-partials -> final top-3 + weights
__global__ __launch_bounds__(256) void knn_merge(const int* __restrict__ pidx,
                                                 const float* __restrict__ pdst,
                                                 int* __restrict__ idxw,
                                                 float* __restrict__ wgt) {
    int m = blockIdx.x * 256 + threadIdx.x;
    float d0 = 1e30f, d1 = 1e30f, d2 = 1e30f;
    int i0 = 0, i1 = 0, i2 = 0;
#pragma unroll
    for (int c = 0; c < NCHUNK; ++c) {
        size_t base = ((size_t)c * MTOT + m) * 3;
#pragma unroll
        for (int s = 0; s < 3; ++s)
            top3_insert(pdst[base + s], pidx[base + s], d0, d1, d2, i0, i1, i2);
    }
    float w0 = 1.0f / fmaxf(d0, 1e-16f);
    float w1 = 1.0f / fmaxf(d1, 1e-16f);
    float w2 = 1.0f / fmaxf(d2, 1e-16f);
    float inv = 1.0f / (w0 + w1 + w2);
    idxw[m * 3 + 0] = i0;  wgt[m * 3 + 0] = w0 * inv;
    idxw[m * 3 + 1] = i1;  wgt[m * 3 + 1] = w1 * inv;
    idxw[m * 3 + 2] = i2;  wgt[m * 3 + 2] = w2 * inv;
}

// ---- kernel 3: G = xb @ Bt1a^T (fp32 out). 16384 x 256, K=256.
__global__ __launch_bounds__(256) void gemm_G(const ushort* __restrict__ A,
                                              const ushort* __restrict__ Bt,
                                              float* __restrict__ G) {
    int wave = threadIdx.x >> 6, lane = threadIdx.x & 63;
    int m0 = blockIdx.x * 64 + wave * 16;
    int lrow = lane & 15;
    int ko = (lane >> 4) * 8;
    const ushort* arow = A + (size_t)(m0 + lrow) * 256 + ko;
    const ushort* bbase = Bt + (size_t)lrow * 256 + ko;

    floatx4 acc[16];
#pragma unroll
    for (int i = 0; i < 16; ++i) acc[i] = (floatx4){0.f, 0.f, 0.f, 0.f};

    for (int k0 = 0; k0 < 256; k0 += 32) {
        short8 af = *(const short8*)(arow + k0);
#pragma unroll
        for (int nt = 0; nt < 16; ++nt) {
            short8 bf = *(const short8*)(bbase + (size_t)nt * 16 * 256 + k0);
            acc[nt] = __builtin_amdgcn_mfma_f32_16x16x32_bf16(af, bf, acc[nt], 0, 0, 0);
        }
    }
    int rbase = (lane >> 4) * 4;
#pragma unroll
    for (int nt = 0; nt < 16; ++nt) {
        int n = nt * 16 + lrow;
#pragma unroll
        for (int r = 0; r < 4; ++r)
            G[(size_t)(m0 + rbase + r) * 256 + n] = acc[nt][r];
    }
}

// ---- kernel 4: fused  h1 = relu(x_skip@W1b + interp(G) + b1);  out = relu(h1@W2 + b2)
#define LDS_STRIDE 264
__global__ __launch_bounds__(256) void fused_kernel(const ushort* __restrict__ xsb,
                                                    const ushort* __restrict__ Bt1b,
                                                    const float* __restrict__ G,
                                                    const int* __restrict__ idxw,
                                                    const float* __restrict__ wgt,
                                                    const float* __restrict__ b1,
                                                    const ushort* __restrict__ Bt2,
                                                    const float* __restrict__ b2,
                                                    float* __restrict__ out) {
    __shared__ ushort h1t[4][16 * LDS_STRIDE];     // 33 KB
    int wave = threadIdx.x >> 6, lane = threadIdx.x & 63;
    int m0 = blockIdx.x * 64 + wave * 16;
    int lrow = lane & 15;
    int ko = (lane >> 4) * 8;
    int rbase = (lane >> 4) * 4;

    floatx4 acc[16];
#pragma unroll
    for (int i = 0; i < 16; ++i) acc[i] = (floatx4){0.f, 0.f, 0.f, 0.f};
    {
        const ushort* arow = xsb + (size_t)(m0 + lrow) * 64 + ko;
        const ushort* bb = Bt1b + lrow * 64 + ko;
        for (int k0 = 0; k0 < 64; k0 += 32) {
            short8 af = *(const short8*)(arow + k0);
#pragma unroll
            for (int nt = 0; nt < 16; ++nt) {
                short8 bf = *(const short8*)(bb + nt * 16 * 64 + k0);
                acc[nt] = __builtin_amdgcn_mfma_f32_16x16x32_bf16(af, bf, acc[nt], 0, 0, 0);
            }
        }
    }

    int gi[4][3]; float gw[4][3];
#pragma unroll
    for (int r = 0; r < 4; ++r) {
        int row = m0 + rbase + r;
#pragma unroll
        for (int k = 0; k < 3; ++k) {
            gi[r][k] = idxw[row * 3 + k];
            gw[r][k] = wgt[row * 3 + k];
        }
    }

    ushort* ht = h1t[wave];
#pragma unroll
    for (int nt = 0; nt < 16; ++nt) {
        int n = nt * 16 + lrow;
        float bv = b1[n];
#pragma unroll
        for (int r = 0; r < 4; ++r) {
            float g = gw[r][0] * G[(size_t)gi[r][0] * 256 + n]
                    + gw[r][1] * G[(size_t)gi[r][1] * 256 + n]
                    + gw[r][2] * G[(size_t)gi[r][2] * 256 + n];
            float v = fmaxf(acc[nt][r] + g + bv, 0.f);
            ht[(rbase + r) * LDS_STRIDE + n] = f2bf(v);
        }
    }

#pragma unroll
    for (int i = 0; i < 16; ++i) acc[i] = (floatx4){0.f, 0.f, 0.f, 0.f};
    {
        const ushort* bb = Bt2 + lrow * 256 + ko;
        const ushort* ar = ht + lrow * LDS_STRIDE + ko;
        for (int k0 = 0; k0 < 256; k0 += 32) {
            short8 af = *(const short8*)(ar + k0);
#pragma unroll
            for (int nt = 0; nt < 16; ++nt) {
                short8 bf = *(const short8*)(bb + nt * 16 * 256 + k0);
                acc[nt] = __builtin_amdgcn_mfma_f32_16x16x32_bf16(af, bf, acc[nt], 0, 0, 0);
            }
        }
    }
#pragma unroll
    for (int nt = 0; nt < 16; ++nt) {
        int n = nt * 16 + lrow;
        float bv = b2[n];
#pragma unroll
        for (int r = 0; r < 4; ++r) {
            float v = fmaxf(acc[nt][r] + bv, 0.f);
            out[(size_t)(m0 + rbase + r) * OUTD + n] = v;
        }
    }
}

// ---- kernel 5: tail outputs (pos_skip copy + batch ids as float)
__global__ __launch_bounds__(256) void tail_kernel(const float* __restrict__ pos_skip,
                                                   float* __restrict__ out) {
    int t = blockIdx.x * 256 + threadIdx.x;
    if (t < MTOT * 3) out[(size_t)MTOT * OUTD + t] = pos_skip[t];
    if (t < MTOT)     out[(size_t)MTOT * OUTD + (size_t)MTOT * 3 + t] = (float)(t >> 13);
}

extern "C" void kernel_launch(void* const* d_in, const int* in_sizes, int n_in,
                              void* d_out, int out_size, void* d_ws, size_t ws_size,
                              hipStream_t stream) {
    const float* x        = (const float*)d_in[0];
    const float* pos      = (const float*)d_in[1];
    const float* x_skip   = (const float*)d_in[3];
    const float* pos_skip = (const float*)d_in[4];
    const float* W1       = (const float*)d_in[6];
    const float* b1       = (const float*)d_in[7];
    const float* W2       = (const float*)d_in[8];
    const float* b2       = (const float*)d_in[9];

    char* ws = (char*)d_ws;
    size_t off = 0;
    int*    idxw = (int*)(ws + off);    off += (size_t)MTOT * 3 * 4;      //  768 KB
    float*  wgt  = (float*)(ws + off);  off += (size_t)MTOT * 3 * 4;      //  768 KB
    ushort* xb   = (ushort*)(ws + off); off += (size_t)NCTOT * 256 * 2;   //    8 MB
    ushort* xsb  = (ushort*)(ws + off); off += (size_t)MTOT * 64 * 2;     //    8 MB
    float*  G    = (float*)(ws + off);  off += (size_t)NCTOT * 256 * 4;   //   16 MB
    ushort* Bt1a = (ushort*)(ws + off); off += (size_t)256 * 256 * 2;     //  128 KB
    ushort* Bt1b = (ushort*)(ws + off); off += (size_t)256 * 64 * 2;      //   32 KB
    ushort* Bt2  = (ushort*)(ws + off); off += (size_t)256 * 256 * 2;     //  128 KB
    float4* pos4 = (float4*)(ws + off); off += (size_t)(NCTOT + 4) * 16;  //  256 KB
    // total ~34 MB (ws-proven). kNN chunk partials ALIAS the G region (dead
    // before gemm_G writes G): pidx 6.3 MB + pdst 6.3 MB < 16 MB.
    int*   pidx = (int*)G;
    float* pdst = (float*)((char*)G + (size_t)NCHUNK * MTOT * 3 * 4);

    float* out = (float*)d_out;

    prep_kernel<<<(PREP_THREADS + 255) / 256, 256, 0, stream>>>(
        x, x_skip, W1, W2, pos, xb, xsb, Bt1a, Bt1b, Bt2, pos4);
    knn_part<<<(MTOT / 256) * NCHUNK, 256, 0, stream>>>(pos4, pos_skip, pidx, pdst);
    knn_merge<<<MTOT / 256, 256, 0, stream>>>(pidx, pdst, idxw, wgt);
    gemm_G<<<NCTOT / 64, 256, 0, stream>>>(xb, Bt1a, G);
    fused_kernel<<<MTOT / 64, 256, 0, stream>>>(xsb, Bt1b, G, idxw, wgt, b1, Bt2, b2, out);
    tail_kernel<<<(MTOT * 3 + 255) / 256, 256, 0, stream>>>(pos_skip, out);
}

// Round 4
// 312.182 us; speedup vs baseline: 2.0712x; 2.0712x over previous
//
#include <hip/hip_runtime.h>
#include <hip/hip_bf16.h>

#define BATCH 8
#define NC 2048
#define NF 8192
#define CDIM 256
#define CSKIP 64
#define OUTD 256
#define MTOT (BATCH*NF)   // 65536
#define NCTOT (BATCH*NC)  // 16384
#define NCHUNK 8          // kNN coarse-scan split
#define CHSZ (NC/NCHUNK)  // 256

typedef __attribute__((ext_vector_type(8))) short short8;
typedef __attribute__((ext_vector_type(4))) float floatx4;

static __device__ __forceinline__ ushort f2bf(float f) {
    union { float f; unsigned u; } v; v.f = f;
    unsigned r = v.u + 0x7fffu + ((v.u >> 16) & 1u);   // RNE
    return (ushort)(r >> 16);
}
static __device__ __forceinline__ float bf2f(ushort u) {
    union { unsigned u; float f; } v; v.u = ((unsigned)u) << 16;
    return v.f;
}

// branchless strict-< top-3 insert (exact match of sequential scan w/ jax top_k ties)
#define TOP3_INSERT(d, jj)                          \
    {                                               \
        bool c2 = (d) < d2, c1 = (d) < d1, c0 = (d) < d0; \
        d2 = c1 ? d1 : (c2 ? (d) : d2);             \
        i2 = c1 ? i1 : (c2 ? (jj) : i2);            \
        d1 = c0 ? d0 : (c1 ? (d) : d1);             \
        i1 = c0 ? i0 : (c1 ? (jj) : i1);            \
        d0 = c0 ? (d) : d0;                         \
        i0 = c0 ? (jj) : i0;                        \
    }

// ---- kernel 1: prep (bf16 casts, weight transposes, pos padding)
#define SEG0 1048576
#define SEG1 1048576
#define SEG2 65536
#define SEG3 16384
#define SEG4 65536
#define SEG5 16384
#define PREP_THREADS (SEG0+SEG1+SEG2+SEG3+SEG4+SEG5)

__global__ __launch_bounds__(256) void prep_kernel(const float* __restrict__ x,
                                                   const float* __restrict__ x_skip,
                                                   const float* __restrict__ W1,
                                                   const float* __restrict__ W2,
                                                   const float* __restrict__ pos,
                                                   ushort* __restrict__ xb,
                                                   ushort* __restrict__ xsb,
                                                   ushort* __restrict__ Bt1a,
                                                   ushort* __restrict__ Bt1b,
                                                   ushort* __restrict__ Bt2,
                                                   float4* __restrict__ pos4) {
    int t = blockIdx.x * 256 + threadIdx.x;
    if (t < SEG0) {
        float4 v = ((const float4*)x)[t];
        ushort4 p; p.x = f2bf(v.x); p.y = f2bf(v.y); p.z = f2bf(v.z); p.w = f2bf(v.w);
        ((ushort4*)xb)[t] = p;
        return;
    }
    t -= SEG0;
    if (t < SEG1) {
        float4 v = ((const float4*)x_skip)[t];
        ushort4 p; p.x = f2bf(v.x); p.y = f2bf(v.y); p.z = f2bf(v.z); p.w = f2bf(v.w);
        ((ushort4*)xsb)[t] = p;
        return;
    }
    t -= SEG1;
    if (t < SEG2) {
        int k = t & 255, n = t >> 8;
        Bt1a[n * 256 + k] = f2bf(W1[k * 256 + n]);
        return;
    }
    t -= SEG2;
    if (t < SEG3) {
        int k2 = t & 63, n = t >> 6;
        Bt1b[n * 64 + k2] = f2bf(W1[(256 + k2) * 256 + n]);
        return;
    }
    t -= SEG3;
    if (t < SEG4) {
        int k = t & 255, n = t >> 8;
        Bt2[n * 256 + k] = f2bf(W2[k * 256 + n]);
        return;
    }
    t -= SEG4;
    if (t < SEG5) {
        float4 q;
        q.x = pos[t * 3 + 0]; q.y = pos[t * 3 + 1]; q.z = pos[t * 3 + 2]; q.w = 0.f;
        pos4[t] = q;
    }
}

// ---- kernel 2a: chunked kNN partials, coarse chunk staged in LDS.
// Round-3 lesson: wave-uniform global loads became s_load through the tiny
// scalar cache (serialized ~100cyc/load -> 345us). LDS broadcast reads avoid
// the scalar path entirely; branchless insert keeps VALU count ~21/candidate.
__global__ __launch_bounds__(256) void knn_part(const float4* __restrict__ pos4,
                                                const float* __restrict__ pos_skip,
                                                int* __restrict__ pidx,
                                                float* __restrict__ pdst) {
    __shared__ float4 spc[CHSZ];                       // 4 KB
    int c = blockIdx.x & (NCHUNK - 1);
    int m = (blockIdx.x >> 3) * 256 + threadIdx.x;
    int b = m >> 13;                                   // NF = 8192
    int jbase = b * NC + c * CHSZ;

    spc[threadIdx.x] = pos4[jbase + threadIdx.x];      // CHSZ == blockDim
    float px = pos_skip[m * 3 + 0];
    float py = pos_skip[m * 3 + 1];
    float pz = pos_skip[m * 3 + 2];
    __syncthreads();

    float d0 = 1e30f, d1 = 1e30f, d2 = 1e30f;
    int i0 = jbase, i1 = jbase, i2 = jbase;
#pragma unroll 4
    for (int j = 0; j < CHSZ; ++j) {
        float4 q = spc[j];
        float dx = px - q.x, dy = py - q.y, dz = pz - q.z;
        float d = dx * dx + dy * dy + dz * dz;
        int jj = jbase + j;
        TOP3_INSERT(d, jj);
    }
    size_t base = ((size_t)c * MTOT + m) * 3;
    pdst[base + 0] = d0; pdst[base + 1] = d1; pdst[base + 2] = d2;
    pidx[base + 0] = i0; pidx[base + 1] = i1; pidx[base + 2] = i2;
}

// ---- kernel 2b: merge 8 chunk-partials -> final top-3 + weights
__global__ __launch_bounds__(64) void knn_merge(const int* __restrict__ pidx,
                                                const float* __restrict__ pdst,
                                                int* __restrict__ idxw,
                                                float* __restrict__ wgt) {
    int m = blockIdx.x * 64 + threadIdx.x;
    float d0 = 1e30f, d1 = 1e30f, d2 = 1e30f;
    int i0 = 0, i1 = 0, i2 = 0;
#pragma unroll
    for (int c = 0; c < NCHUNK; ++c) {
        size_t base = ((size_t)c * MTOT + m) * 3;
#pragma unroll
        for (int s = 0; s < 3; ++s) {
            float d = pdst[base + s];
            int jj = pidx[base + s];
            TOP3_INSERT(d, jj);
        }
    }
    float w0 = 1.0f / fmaxf(d0, 1e-16f);
    float w1 = 1.0f / fmaxf(d1, 1e-16f);
    float w2 = 1.0f / fmaxf(d2, 1e-16f);
    float inv = 1.0f / (w0 + w1 + w2);
    idxw[m * 3 + 0] = i0;  wgt[m * 3 + 0] = w0 * inv;
    idxw[m * 3 + 1] = i1;  wgt[m * 3 + 1] = w1 * inv;
    idxw[m * 3 + 2] = i2;  wgt[m * 3 + 2] = w2 * inv;
}

// ---- kernel 3: G = xb @ Bt1a^T (fp32 out). 16384 x 256, K=256.
// Column-split: wave w of each block covers nt in [4w, 4w+4); grid 1024 (4 blk/CU).
__global__ __launch_bounds__(256) void gemm_G(const ushort* __restrict__ A,
                                              const ushort* __restrict__ Bt,
                                              float* __restrict__ G) {
    int wave = threadIdx.x >> 6, lane = threadIdx.x & 63;
    int m0 = blockIdx.x * 16;
    int lrow = lane & 15;
    int ko = (lane >> 4) * 8;
    const ushort* arow = A + (size_t)(m0 + lrow) * 256 + ko;
    const ushort* bbase = Bt + (size_t)(wave * 64 + lrow) * 256 + ko;

    floatx4 acc[4];
#pragma unroll
    for (int i = 0; i < 4; ++i) acc[i] = (floatx4){0.f, 0.f, 0.f, 0.f};

    for (int k0 = 0; k0 < 256; k0 += 32) {
        short8 af = *(const short8*)(arow + k0);
#pragma unroll
        for (int nt = 0; nt < 4; ++nt) {
            short8 bf = *(const short8*)(bbase + (size_t)nt * 16 * 256 + k0);
            acc[nt] = __builtin_amdgcn_mfma_f32_16x16x32_bf16(af, bf, acc[nt], 0, 0, 0);
        }
    }
    int rbase = (lane >> 4) * 4;
#pragma unroll
    for (int nt = 0; nt < 4; ++nt) {
        int n = wave * 64 + nt * 16 + lrow;
#pragma unroll
        for (int r = 0; r < 4; ++r)
            G[(size_t)(m0 + rbase + r) * 256 + n] = acc[nt][r];
    }
}

// ---- kernel 4: fused  h1 = relu(x_skip@W1b + interp(G) + b1);  out = relu(h1@W2 + b2)
// Stage 2 is cooperative: lane owns cols 4L..4L+3 -> G gathers are coalesced
// float4 loads (48/wave) instead of 192 scalar loads (round-3 version).
#define LDS_STRIDE 264
__global__ __launch_bounds__(256) void fused_kernel(const ushort* __restrict__ xsb,
                                                    const ushort* __restrict__ Bt1b,
                                                    const float* __restrict__ G,
                                                    const int* __restrict__ idxw,
                                                    const float* __restrict__ wgt,
                                                    const float* __restrict__ b1,
                                                    const ushort* __restrict__ Bt2,
                                                    const float* __restrict__ b2,
                                                    float* __restrict__ out) {
    __shared__ ushort h1t[4][16 * LDS_STRIDE];     // 33 KB
    int wave = threadIdx.x >> 6, lane = threadIdx.x & 63;
    int m0 = blockIdx.x * 64 + wave * 16;
    int lrow = lane & 15;
    int ko = (lane >> 4) * 8;
    int rbase = (lane >> 4) * 4;

    // ---- stage 1: S = x_skip_tile @ W1b^T  (K=64)
    floatx4 acc[16];
#pragma unroll
    for (int i = 0; i < 16; ++i) acc[i] = (floatx4){0.f, 0.f, 0.f, 0.f};
    {
        const ushort* arow = xsb + (size_t)(m0 + lrow) * 64 + ko;
        const ushort* bb = Bt1b + lrow * 64 + ko;
        for (int k0 = 0; k0 < 64; k0 += 32) {
            short8 af = *(const short8*)(arow + k0);
#pragma unroll
            for (int nt = 0; nt < 16; ++nt) {
                short8 bf = *(const short8*)(bb + nt * 16 * 64 + k0);
                acc[nt] = __builtin_amdgcn_mfma_f32_16x16x32_bf16(af, bf, acc[nt], 0, 0, 0);
            }
        }
    }

    // ---- stage 2a: S (bf16) -> wave-private LDS tile at C-layout positions
    ushort* ht = h1t[wave];
#pragma unroll
    for (int nt = 0; nt < 16; ++nt) {
        int n = nt * 16 + lrow;
#pragma unroll
        for (int r = 0; r < 4; ++r)
            ht[(rbase + r) * LDS_STRIDE + n] = f2bf(acc[nt][r]);
    }

    // ---- stage 2b: cooperative interp + bias + relu; lane owns cols 4L..4L+3
    float4 bv = ((const float4*)b1)[lane];
    const float4* Gv = (const float4*)G;
#pragma unroll 4
    for (int i = 0; i < 16; ++i) {
        int row = m0 + i;
        int j0 = idxw[row * 3 + 0], j1 = idxw[row * 3 + 1], j2 = idxw[row * 3 + 2];
        float w0 = wgt[row * 3 + 0], w1 = wgt[row * 3 + 1], w2 = wgt[row * 3 + 2];
        float4 g0 = Gv[(size_t)j0 * 64 + lane];
        float4 g1 = Gv[(size_t)j1 * 64 + lane];
        float4 g2 = Gv[(size_t)j2 * 64 + lane];
        ushort4 sv = *(const ushort4*)(ht + i * LDS_STRIDE + 4 * lane);
        float4 h;
        h.x = fmaxf(bf2f(sv.x) + w0 * g0.x + w1 * g1.x + w2 * g2.x + bv.x, 0.f);
        h.y = fmaxf(bf2f(sv.y) + w0 * g0.y + w1 * g1.y + w2 * g2.y + bv.y, 0.f);
        h.z = fmaxf(bf2f(sv.z) + w0 * g0.z + w1 * g1.z + w2 * g2.z + bv.z, 0.f);
        h.w = fmaxf(bf2f(sv.w) + w0 * g0.w + w1 * g1.w + w2 * g2.w + bv.w, 0.f);
        ushort4 hp;
        hp.x = f2bf(h.x); hp.y = f2bf(h.y); hp.z = f2bf(h.z); hp.w = f2bf(h.w);
        *(ushort4*)(ht + i * LDS_STRIDE + 4 * lane) = hp;
    }

    // ---- stage 3: out = relu(h1 @ W2^T + b2)  (K=256), A from own LDS tile
#pragma unroll
    for (int i = 0; i < 16; ++i) acc[i] = (floatx4){0.f, 0.f, 0.f, 0.f};
    {
        const ushort* bb = Bt2 + lrow * 256 + ko;
        const ushort* ar = ht + lrow * LDS_STRIDE + ko;
        for (int k0 = 0; k0 < 256; k0 += 32) {
            short8 af = *(const short8*)(ar + k0);
#pragma unroll
            for (int nt = 0; nt < 16; ++nt) {
                short8 bf = *(const short8*)(bb + nt * 16 * 256 + k0);
                acc[nt] = __builtin_amdgcn_mfma_f32_16x16x32_bf16(af, bf, acc[nt], 0, 0, 0);
            }
        }
    }
#pragma unroll
    for (int nt = 0; nt < 16; ++nt) {
        int n = nt * 16 + lrow;
        float bv2 = b2[n];
#pragma unroll
        for (int r = 0; r < 4; ++r) {
            float v = fmaxf(acc[nt][r] + bv2, 0.f);
            out[(size_t)(m0 + rbase + r) * OUTD + n] = v;
        }
    }
}

// ---- kernel 5: tail outputs (pos_skip copy + batch ids as float)
__global__ __launch_bounds__(256) void tail_kernel(const float* __restrict__ pos_skip,
                                                   float* __restrict__ out) {
    int t = blockIdx.x * 256 + threadIdx.x;
    if (t < MTOT * 3) out[(size_t)MTOT * OUTD + t] = pos_skip[t];
    if (t < MTOT)     out[(size_t)MTOT * OUTD + (size_t)MTOT * 3 + t] = (float)(t >> 13);
}

extern "C" void kernel_launch(void* const* d_in, const int* in_sizes, int n_in,
                              void* d_out, int out_size, void* d_ws, size_t ws_size,
                              hipStream_t stream) {
    const float* x        = (const float*)d_in[0];
    const float* pos      = (const float*)d_in[1];
    const float* x_skip   = (const float*)d_in[3];
    const float* pos_skip = (const float*)d_in[4];
    const float* W1       = (const float*)d_in[6];
    const float* b1       = (const float*)d_in[7];
    const float* W2       = (const float*)d_in[8];
    const float* b2       = (const float*)d_in[9];

    char* ws = (char*)d_ws;
    size_t off = 0;
    int*    idxw = (int*)(ws + off);    off += (size_t)MTOT * 3 * 4;      //  768 KB
    float*  wgt  = (float*)(ws + off);  off += (size_t)MTOT * 3 * 4;      //  768 KB
    ushort* xb   = (ushort*)(ws + off); off += (size_t)NCTOT * 256 * 2;   //    8 MB
    ushort* xsb  = (ushort*)(ws + off); off += (size_t)MTOT * 64 * 2;     //    8 MB
    float*  G    = (float*)(ws + off);  off += (size_t)NCTOT * 256 * 4;   //   16 MB
    ushort* Bt1a = (ushort*)(ws + off); off += (size_t)256 * 256 * 2;     //  128 KB
    ushort* Bt1b = (ushort*)(ws + off); off += (size_t)256 * 64 * 2;      //   32 KB
    ushort* Bt2  = (ushort*)(ws + off); off += (size_t)256 * 256 * 2;     //  128 KB
    float4* pos4 = (float4*)(ws + off); off += (size_t)(NCTOT + 4) * 16;  //  256 KB
    // total ~34 MB (ws-proven). kNN chunk partials ALIAS the G region (dead
    // before gemm_G writes G): pidx 6.3 MB + pdst 6.3 MB < 16 MB.
    int*   pidx = (int*)G;
    float* pdst = (float*)((char*)G + (size_t)NCHUNK * MTOT * 3 * 4);

    float* out = (float*)d_out;

    prep_kernel<<<(PREP_THREADS + 255) / 256, 256, 0, stream>>>(
        x, x_skip, W1, W2, pos, xb, xsb, Bt1a, Bt1b, Bt2, pos4);
    knn_part<<<(MTOT / 256) * NCHUNK, 256, 0, stream>>>(pos4, pos_skip, pidx, pdst);
    knn_merge<<<MTOT / 64, 64, 0, stream>>>(pidx, pdst, idxw, wgt);
    gemm_G<<<NCTOT / 16, 256, 0, stream>>>(xb, Bt1a, G);
    fused_kernel<<<MTOT / 64, 256, 0, stream>>>(xsb, Bt1b, G, idxw, wgt, b1, Bt2, b2, out);
    tail_kernel<<<(MTOT * 3 + 255) / 256, 256, 0, stream>>>(pos_skip, out);
}

// Round 5
// 305.570 us; speedup vs baseline: 2.1160x; 1.0216x over previous
//
#include <hip/hip_runtime.h>
#include <hip/hip_bf16.h>

#define BATCH 8
#define NC 2048
#define NF 8192
#define CDIM 256
#define CSKIP 64
#define OUTD 256
#define MTOT (BATCH*NF)   // 65536
#define NCTOT (BATCH*NC)  // 16384
#define NCHUNK 8          // kNN coarse-scan split
#define CHSZ (NC/NCHUNK)  // 256

typedef __attribute__((ext_vector_type(8))) short short8;
typedef __attribute__((ext_vector_type(4))) float floatx4;

static __device__ __forceinline__ ushort f2bf(float f) {
    union { float f; unsigned u; } v; v.f = f;
    unsigned r = v.u + 0x7fffu + ((v.u >> 16) & 1u);   // RNE
    return (ushort)(r >> 16);
}
static __device__ __forceinline__ float bf2f(ushort u) {
    union { unsigned u; float f; } v; v.u = ((unsigned)u) << 16;
    return v.f;
}

// branchless strict-< top-3 insert (exact match of sequential scan w/ jax top_k ties)
#define TOP3_INSERT(d, jj)                          \
    {                                               \
        bool c2 = (d) < d2, c1 = (d) < d1, c0 = (d) < d0; \
        d2 = c1 ? d1 : (c2 ? (d) : d2);             \
        i2 = c1 ? i1 : (c2 ? (jj) : i2);            \
        d1 = c0 ? d0 : (c1 ? (d) : d1);             \
        i1 = c0 ? i0 : (c1 ? (jj) : i1);            \
        d0 = c0 ? (d) : d0;                         \
        i0 = c0 ? (jj) : i0;                        \
    }

// ---- kernel 1: prep (bf16 casts, weight transposes, pos padding, tail outputs)
#define SEG0 1048576   // x -> xb bf16 (float4-wide)
#define SEG1 1048576   // x_skip -> xsb bf16
#define SEG2 65536     // W1[0:256,:]  -> Bt1a[n][k]
#define SEG3 16384     // W1[256:320,:]-> Bt1b[n][k2]
#define SEG4 65536     // W2 -> Bt2[n][k]
#define SEG5 16384     // pos -> pos4
#define SEG6 (MTOT*3)  // pos_skip -> out tail
#define SEG7 MTOT      // batch ids -> out tail
#define PREP_THREADS (SEG0+SEG1+SEG2+SEG3+SEG4+SEG5+SEG6+SEG7)

__global__ __launch_bounds__(256) void prep_kernel(const float* __restrict__ x,
                                                   const float* __restrict__ x_skip,
                                                   const float* __restrict__ W1,
                                                   const float* __restrict__ W2,
                                                   const float* __restrict__ pos,
                                                   const float* __restrict__ pos_skip,
                                                   ushort* __restrict__ xb,
                                                   ushort* __restrict__ xsb,
                                                   ushort* __restrict__ Bt1a,
                                                   ushort* __restrict__ Bt1b,
                                                   ushort* __restrict__ Bt2,
                                                   float4* __restrict__ pos4,
                                                   float* __restrict__ out) {
    int t = blockIdx.x * 256 + threadIdx.x;
    if (t < SEG0) {
        float4 v = ((const float4*)x)[t];
        ushort4 p; p.x = f2bf(v.x); p.y = f2bf(v.y); p.z = f2bf(v.z); p.w = f2bf(v.w);
        ((ushort4*)xb)[t] = p;
        return;
    }
    t -= SEG0;
    if (t < SEG1) {
        float4 v = ((const float4*)x_skip)[t];
        ushort4 p; p.x = f2bf(v.x); p.y = f2bf(v.y); p.z = f2bf(v.z); p.w = f2bf(v.w);
        ((ushort4*)xsb)[t] = p;
        return;
    }
    t -= SEG1;
    if (t < SEG2) {
        int k = t & 255, n = t >> 8;
        Bt1a[n * 256 + k] = f2bf(W1[k * 256 + n]);
        return;
    }
    t -= SEG2;
    if (t < SEG3) {
        int k2 = t & 63, n = t >> 6;
        Bt1b[n * 64 + k2] = f2bf(W1[(256 + k2) * 256 + n]);
        return;
    }
    t -= SEG3;
    if (t < SEG4) {
        int k = t & 255, n = t >> 8;
        Bt2[n * 256 + k] = f2bf(W2[k * 256 + n]);
        return;
    }
    t -= SEG4;
    if (t < SEG5) {
        float4 q;
        q.x = pos[t * 3 + 0]; q.y = pos[t * 3 + 1]; q.z = pos[t * 3 + 2]; q.w = 0.f;
        pos4[t] = q;
        return;
    }
    t -= SEG5;
    if (t < SEG6) {
        out[(size_t)MTOT * OUTD + t] = pos_skip[t];
        return;
    }
    t -= SEG6;
    if (t < SEG7) {
        out[(size_t)MTOT * OUTD + (size_t)MTOT * 3 + t] = (float)(t >> 13);
    }
}

// ---- kernel 2a: chunked kNN partials, coarse chunk staged in LDS.
// (round-3 lesson: wave-uniform GLOBAL loads become serialized s_loads; LDS
// broadcast reads are the fix. Partials live in d_out[0:12.6MB] — dead before
// fused_kernel overwrites that region.)
__global__ __launch_bounds__(256) void knn_part(const float4* __restrict__ pos4,
                                                const float* __restrict__ pos_skip,
                                                int* __restrict__ pidx,
                                                float* __restrict__ pdst) {
    __shared__ float4 spc[CHSZ];                       // 4 KB
    int c = blockIdx.x & (NCHUNK - 1);
    int m = (blockIdx.x >> 3) * 256 + threadIdx.x;
    int b = m >> 13;                                   // NF = 8192
    int jbase = b * NC + c * CHSZ;

    spc[threadIdx.x] = pos4[jbase + threadIdx.x];      // CHSZ == blockDim
    float px = pos_skip[m * 3 + 0];
    float py = pos_skip[m * 3 + 1];
    float pz = pos_skip[m * 3 + 2];
    __syncthreads();

    float d0 = 1e30f, d1 = 1e30f, d2 = 1e30f;
    int i0 = jbase, i1 = jbase, i2 = jbase;
#pragma unroll 4
    for (int j = 0; j < CHSZ; ++j) {
        float4 q = spc[j];
        float dx = px - q.x, dy = py - q.y, dz = pz - q.z;
        float d = dx * dx + dy * dy + dz * dz;
        int jj = jbase + j;
        TOP3_INSERT(d, jj);
    }
    size_t base = ((size_t)c * MTOT + m) * 3;
    pdst[base + 0] = d0; pdst[base + 1] = d1; pdst[base + 2] = d2;
    pidx[base + 0] = i0; pidx[base + 1] = i1; pidx[base + 2] = i2;
}

// ---- kernel 2b: merge 8 chunk-partials -> final top-3 + weights
__global__ __launch_bounds__(64) void knn_merge(const int* __restrict__ pidx,
                                                const float* __restrict__ pdst,
                                                int* __restrict__ idxw,
                                                float* __restrict__ wgt) {
    int m = blockIdx.x * 64 + threadIdx.x;
    float d0 = 1e30f, d1 = 1e30f, d2 = 1e30f;
    int i0 = 0, i1 = 0, i2 = 0;
#pragma unroll
    for (int c = 0; c < NCHUNK; ++c) {
        size_t base = ((size_t)c * MTOT + m) * 3;
#pragma unroll
        for (int s = 0; s < 3; ++s) {
            float d = pdst[base + s];
            int jj = pidx[base + s];
            TOP3_INSERT(d, jj);
        }
    }
    float w0 = 1.0f / fmaxf(d0, 1e-16f);
    float w1 = 1.0f / fmaxf(d1, 1e-16f);
    float w2 = 1.0f / fmaxf(d2, 1e-16f);
    float inv = 1.0f / (w0 + w1 + w2);
    idxw[m * 3 + 0] = i0;  wgt[m * 3 + 0] = w0 * inv;
    idxw[m * 3 + 1] = i1;  wgt[m * 3 + 1] = w1 * inv;
    idxw[m * 3 + 2] = i2;  wgt[m * 3 + 2] = w2 * inv;
}

// ---- kernel 3: Gb = bf16( xb @ Bt1a^T ). 16384 x 256, K=256.
// bf16 output halves fused-kernel gather bytes (96 MB instead of 192 MB).
__global__ __launch_bounds__(256) void gemm_G(const ushort* __restrict__ A,
                                              const ushort* __restrict__ Bt,
                                              ushort* __restrict__ Gb) {
    int wave = threadIdx.x >> 6, lane = threadIdx.x & 63;
    int m0 = blockIdx.x * 16;
    int lrow = lane & 15;
    int ko = (lane >> 4) * 8;
    const ushort* arow = A + (size_t)(m0 + lrow) * 256 + ko;
    const ushort* bbase = Bt + (size_t)(wave * 64 + lrow) * 256 + ko;

    floatx4 acc[4];
#pragma unroll
    for (int i = 0; i < 4; ++i) acc[i] = (floatx4){0.f, 0.f, 0.f, 0.f};

    for (int k0 = 0; k0 < 256; k0 += 32) {
        short8 af = *(const short8*)(arow + k0);
#pragma unroll
        for (int nt = 0; nt < 4; ++nt) {
            short8 bf = *(const short8*)(bbase + (size_t)nt * 16 * 256 + k0);
            acc[nt] = __builtin_amdgcn_mfma_f32_16x16x32_bf16(af, bf, acc[nt], 0, 0, 0);
        }
    }
    int rbase = (lane >> 4) * 4;
#pragma unroll
    for (int nt = 0; nt < 4; ++nt) {
        int n = wave * 64 + nt * 16 + lrow;
#pragma unroll
        for (int r = 0; r < 4; ++r)
            Gb[(size_t)(m0 + rbase + r) * 256 + n] = f2bf(acc[nt][r]);
    }
}

// ---- kernel 4: fused  h1 = relu(x_skip@W1b + interp(Gb) + b1);  out = relu(h1@W2 + b2)
// Round-4 lesson: wave-uniform idxw/wgt reads became s_loads -> scalar-cache
// serialization dominating (118us, all pipes <15%). Fix: lanes 0..47 load the
// wave's 48 idx+wgt via ONE coalesced vector load each -> wave-private LDS ->
// ds_read broadcast. All gather addresses known up-front; depth-4 pipeline.
#define LDS_STRIDE 264
__global__ __launch_bounds__(256) void fused_kernel(const ushort* __restrict__ xsb,
                                                    const ushort* __restrict__ Bt1b,
                                                    const ushort* __restrict__ Gb,
                                                    const int* __restrict__ idxw,
                                                    const float* __restrict__ wgt,
                                                    const float* __restrict__ b1,
                                                    const ushort* __restrict__ Bt2,
                                                    const float* __restrict__ b2,
                                                    float* __restrict__ out) {
    __shared__ ushort h1t[4][16 * LDS_STRIDE];     // 33 KB
    __shared__ int   sIdx[4][48];
    __shared__ float sWgt[4][48];
    int wave = threadIdx.x >> 6, lane = threadIdx.x & 63;
    int m0 = blockIdx.x * 64 + wave * 16;
    int lrow = lane & 15;
    int ko = (lane >> 4) * 8;
    int rbase = (lane >> 4) * 4;

    // ---- phase 0: idx/wgt -> wave-private LDS via the VECTOR path
    if (lane < 48) {
        sIdx[wave][lane] = idxw[m0 * 3 + lane];
        sWgt[wave][lane] = wgt[m0 * 3 + lane];
    }
    // (same-wave LDS RAW: no barrier needed; stage-1 MFMA hides the latency)

    // ---- stage 1: S = x_skip_tile @ W1b^T  (K=64)
    floatx4 acc[16];
#pragma unroll
    for (int i = 0; i < 16; ++i) acc[i] = (floatx4){0.f, 0.f, 0.f, 0.f};
    {
        const ushort* arow = xsb + (size_t)(m0 + lrow) * 64 + ko;
        const ushort* bb = Bt1b + lrow * 64 + ko;
        for (int k0 = 0; k0 < 64; k0 += 32) {
            short8 af = *(const short8*)(arow + k0);
#pragma unroll
            for (int nt = 0; nt < 16; ++nt) {
                short8 bf = *(const short8*)(bb + nt * 16 * 64 + k0);
                acc[nt] = __builtin_amdgcn_mfma_f32_16x16x32_bf16(af, bf, acc[nt], 0, 0, 0);
            }
        }
    }

    // ---- stage 2a: S (bf16) -> wave-private LDS tile at C-layout positions
    ushort* ht = h1t[wave];
#pragma unroll
    for (int nt = 0; nt < 16; ++nt) {
        int n = nt * 16 + lrow;
#pragma unroll
        for (int r = 0; r < 4; ++r)
            ht[(rbase + r) * LDS_STRIDE + n] = f2bf(acc[nt][r]);
    }

    // ---- stage 2b: cooperative interp (lane owns cols 4L..4L+3), depth-4 pipeline
    {
        const ushort4* Gv = (const ushort4*)Gb;
        const int*   si = sIdx[wave];
        const float* sw = sWgt[wave];
        float4 bv = ((const float4*)b1)[lane];
        ushort4 g[4][3];
#define GATHER(slot, i) {                                         \
        int a0 = si[(i) * 3 + 0];                                 \
        int a1 = si[(i) * 3 + 1];                                 \
        int a2 = si[(i) * 3 + 2];                                 \
        g[slot][0] = Gv[(size_t)a0 * 64 + lane];                  \
        g[slot][1] = Gv[(size_t)a1 * 64 + lane];                  \
        g[slot][2] = Gv[(size_t)a2 * 64 + lane]; }
#define COMBINE(i) {                                              \
        int s = (i) & 3;                                          \
        float w0 = sw[(i) * 3 + 0], w1 = sw[(i) * 3 + 1], w2 = sw[(i) * 3 + 2]; \
        ushort4 sv = *(const ushort4*)(ht + (i) * LDS_STRIDE + 4 * lane); \
        float4 h;                                                 \
        h.x = fmaxf(bf2f(sv.x) + w0 * bf2f(g[s][0].x) + w1 * bf2f(g[s][1].x) + w2 * bf2f(g[s][2].x) + bv.x, 0.f); \
        h.y = fmaxf(bf2f(sv.y) + w0 * bf2f(g[s][0].y) + w1 * bf2f(g[s][1].y) + w2 * bf2f(g[s][2].y) + bv.y, 0.f); \
        h.z = fmaxf(bf2f(sv.z) + w0 * bf2f(g[s][0].z) + w1 * bf2f(g[s][1].z) + w2 * bf2f(g[s][2].z) + bv.z, 0.f); \
        h.w = fmaxf(bf2f(sv.w) + w0 * bf2f(g[s][0].w) + w1 * bf2f(g[s][1].w) + w2 * bf2f(g[s][2].w) + bv.w, 0.f); \
        ushort4 hp;                                               \
        hp.x = f2bf(h.x); hp.y = f2bf(h.y); hp.z = f2bf(h.z); hp.w = f2bf(h.w); \
        *(ushort4*)(ht + (i) * LDS_STRIDE + 4 * lane) = hp; }

        GATHER(0, 0) GATHER(1, 1) GATHER(2, 2) GATHER(3, 3)
#pragma unroll
        for (int i = 0; i < 12; ++i) { COMBINE(i); GATHER(i & 3, i + 4); }
#pragma unroll
        for (int i = 12; i < 16; ++i) { COMBINE(i); }
#undef GATHER
#undef COMBINE
    }

    // ---- stage 3: out = relu(h1 @ W2^T + b2)  (K=256), A from own LDS tile
#pragma unroll
    for (int i = 0; i < 16; ++i) acc[i] = (floatx4){0.f, 0.f, 0.f, 0.f};
    {
        const ushort* bb = Bt2 + lrow * 256 + ko;
        const ushort* ar = ht + lrow * LDS_STRIDE + ko;
        for (int k0 = 0; k0 < 256; k0 += 32) {
            short8 af = *(const short8*)(ar + k0);
#pragma unroll
            for (int nt = 0; nt < 16; ++nt) {
                short8 bf = *(const short8*)(bb + nt * 16 * 256 + k0);
                acc[nt] = __builtin_amdgcn_mfma_f32_16x16x32_bf16(af, bf, acc[nt], 0, 0, 0);
            }
        }
    }
#pragma unroll
    for (int nt = 0; nt < 16; ++nt) {
        int n = nt * 16 + lrow;
        float bv2 = b2[n];
#pragma unroll
        for (int r = 0; r < 4; ++r) {
            float v = fmaxf(acc[nt][r] + bv2, 0.f);
            out[(size_t)(m0 + rbase + r) * OUTD + n] = v;
        }
    }
}

extern "C" void kernel_launch(void* const* d_in, const int* in_sizes, int n_in,
                              void* d_out, int out_size, void* d_ws, size_t ws_size,
                              hipStream_t stream) {
    const float* x        = (const float*)d_in[0];
    const float* pos      = (const float*)d_in[1];
    const float* x_skip   = (const float*)d_in[3];
    const float* pos_skip = (const float*)d_in[4];
    const float* W1       = (const float*)d_in[6];
    const float* b1       = (const float*)d_in[7];
    const float* W2       = (const float*)d_in[8];
    const float* b2       = (const float*)d_in[9];

    char* ws = (char*)d_ws;
    size_t off = 0;
    int*    idxw = (int*)(ws + off);    off += (size_t)MTOT * 3 * 4;      //  768 KB
    float*  wgt  = (float*)(ws + off);  off += (size_t)MTOT * 3 * 4;      //  768 KB
    ushort* xb   = (ushort*)(ws + off); off += (size_t)NCTOT * 256 * 2;   //    8 MB
    ushort* xsb  = (ushort*)(ws + off); off += (size_t)MTOT * 64 * 2;     //    8 MB
    ushort* Gb   = (ushort*)(ws + off); off += (size_t)NCTOT * 256 * 2;   //    8 MB
    ushort* Bt1a = (ushort*)(ws + off); off += (size_t)256 * 256 * 2;     //  128 KB
    ushort* Bt1b = (ushort*)(ws + off); off += (size_t)256 * 64 * 2;      //   32 KB
    ushort* Bt2  = (ushort*)(ws + off); off += (size_t)256 * 256 * 2;     //  128 KB
    float4* pos4 = (float4*)(ws + off); off += (size_t)(NCTOT + 4) * 16;  //  256 KB
    // total ~26 MB (well inside the proven 34 MB budget).
    // kNN chunk partials live in d_out[0 : 12.6 MB]: written by knn_part, read
    // by knn_merge, then fully overwritten by fused_kernel's h-output. The out
    // tail region (>=64 MB) is disjoint.
    float* out = (float*)d_out;
    int*   pidx = (int*)d_out;
    float* pdst = (float*)((char*)d_out + (size_t)NCHUNK * MTOT * 3 * 4);

    prep_kernel<<<(PREP_THREADS + 255) / 256, 256, 0, stream>>>(
        x, x_skip, W1, W2, pos, pos_skip, xb, xsb, Bt1a, Bt1b, Bt2, pos4, out);
    knn_part<<<(MTOT / 256) * NCHUNK, 256, 0, stream>>>(pos4, pos_skip, pidx, pdst);
    knn_merge<<<MTOT / 64, 64, 0, stream>>>(pidx, pdst, idxw, wgt);
    gemm_G<<<NCTOT / 16, 256, 0, stream>>>(xb, Bt1a, Gb);
    fused_kernel<<<MTOT / 64, 256, 0, stream>>>(xsb, Bt1b, Gb, idxw, wgt, b1, Bt2, b2, out);
}

// Round 6
// 229.295 us; speedup vs baseline: 2.8199x; 1.3326x over previous
//
#include <hip/hip_runtime.h>
#include <hip/hip_bf16.h>

#define BATCH 8
#define NC 2048
#define NF 8192
#define CDIM 256
#define CSKIP 64
#define OUTD 256
#define MTOT (BATCH*NF)   // 65536
#define NCTOT (BATCH*NC)  // 16384
#define NCHUNK 8          // kNN coarse-scan split
#define CHSZ (NC/NCHUNK)  // 256

typedef __attribute__((ext_vector_type(8))) short short8;
typedef __attribute__((ext_vector_type(4))) float floatx4;

static __device__ __forceinline__ ushort f2bf(float f) {
    union { float f; unsigned u; } v; v.f = f;
    unsigned r = v.u + 0x7fffu + ((v.u >> 16) & 1u);   // RNE
    return (ushort)(r >> 16);
}
static __device__ __forceinline__ float bf2f(ushort u) {
    union { unsigned u; float f; } v; v.u = ((unsigned)u) << 16;
    return v.f;
}

#if defined(__has_builtin) && __has_builtin(__builtin_amdgcn_fmed3f)
#define MED3F(a, b, c) __builtin_amdgcn_fmed3f((a), (b), (c))
#else
static __device__ __forceinline__ float MED3F(float a, float b, float c) {
    return fmaxf(fminf(a, b), fminf(fmaxf(a, b), c));
}
#endif

// branchless strict-< top-3 insert (exact match of sequential scan w/ jax top_k ties)
#define TOP3_INSERT(d, jj)                          \
    {                                               \
        bool c2 = (d) < d2, c1 = (d) < d1, c0 = (d) < d0; \
        i2 = c1 ? i1 : (c2 ? (jj) : i2);            \
        i1 = c0 ? i0 : (c1 ? (jj) : i1);            \
        i0 = c0 ? (jj) : i0;                        \
        d2 = MED3F(d1, d2, (d));                    \
        d1 = MED3F(d0, d1, (d));                    \
        d0 = fminf(d0, (d));                        \
    }

// ---- kernel 1: prep (bf16 casts, weight transposes, pos padding, tail outputs)
#define SEG0 1048576   // x -> xb bf16 (float4-wide)
#define SEG1 1048576   // x_skip -> xsb bf16
#define SEG2 65536     // W1[0:256,:]  -> Bt1a[n][k]
#define SEG3 16384     // W1[256:320,:]-> Bt1b[n][k2]
#define SEG4 65536     // W2 -> Bt2[n][k]
#define SEG5 16384     // pos -> pos4
#define SEG6 (MTOT*3)  // pos_skip -> out tail
#define SEG7 MTOT      // batch ids -> out tail
#define PREP_THREADS (SEG0+SEG1+SEG2+SEG3+SEG4+SEG5+SEG6+SEG7)

__global__ __launch_bounds__(256) void prep_kernel(const float* __restrict__ x,
                                                   const float* __restrict__ x_skip,
                                                   const float* __restrict__ W1,
                                                   const float* __restrict__ W2,
                                                   const float* __restrict__ pos,
                                                   const float* __restrict__ pos_skip,
                                                   ushort* __restrict__ xb,
                                                   ushort* __restrict__ xsb,
                                                   ushort* __restrict__ Bt1a,
                                                   ushort* __restrict__ Bt1b,
                                                   ushort* __restrict__ Bt2,
                                                   float4* __restrict__ pos4,
                                                   float* __restrict__ out) {
    int t = blockIdx.x * 256 + threadIdx.x;
    if (t < SEG0) {
        float4 v = ((const float4*)x)[t];
        ushort4 p; p.x = f2bf(v.x); p.y = f2bf(v.y); p.z = f2bf(v.z); p.w = f2bf(v.w);
        ((ushort4*)xb)[t] = p;
        return;
    }
    t -= SEG0;
    if (t < SEG1) {
        float4 v = ((const float4*)x_skip)[t];
        ushort4 p; p.x = f2bf(v.x); p.y = f2bf(v.y); p.z = f2bf(v.z); p.w = f2bf(v.w);
        ((ushort4*)xsb)[t] = p;
        return;
    }
    t -= SEG1;
    if (t < SEG2) {
        int k = t & 255, n = t >> 8;
        Bt1a[n * 256 + k] = f2bf(W1[k * 256 + n]);
        return;
    }
    t -= SEG2;
    if (t < SEG3) {
        int k2 = t & 63, n = t >> 6;
        Bt1b[n * 64 + k2] = f2bf(W1[(256 + k2) * 256 + n]);
        return;
    }
    t -= SEG3;
    if (t < SEG4) {
        int k = t & 255, n = t >> 8;
        Bt2[n * 256 + k] = f2bf(W2[k * 256 + n]);
        return;
    }
    t -= SEG4;
    if (t < SEG5) {
        float4 q;
        q.x = pos[t * 3 + 0]; q.y = pos[t * 3 + 1]; q.z = pos[t * 3 + 2]; q.w = 0.f;
        pos4[t] = q;
        return;
    }
    t -= SEG5;
    if (t < SEG6) {
        out[(size_t)MTOT * OUTD + t] = pos_skip[t];
        return;
    }
    t -= SEG6;
    if (t < SEG7) {
        out[(size_t)MTOT * OUTD + (size_t)MTOT * 3 + t] = (float)(t >> 13);
    }
}

// ---- kernel 2a: chunked kNN partials. SoA coarse chunk in LDS (3 b128 reads
// per 4 candidates) + med3-based branchless insert (~18 VALU/candidate).
__global__ __launch_bounds__(256) void knn_part(const float4* __restrict__ pos4,
                                                const float* __restrict__ pos_skip,
                                                int* __restrict__ pidx,
                                                float* __restrict__ pdst) {
    __shared__ float sx[CHSZ], sy[CHSZ], sz[CHSZ];     // 3 KB
    int c = blockIdx.x & (NCHUNK - 1);
    int m = (blockIdx.x >> 3) * 256 + threadIdx.x;
    int b = m >> 13;                                   // NF = 8192
    int jbase = b * NC + c * CHSZ;

    float4 q0 = pos4[jbase + threadIdx.x];
    sx[threadIdx.x] = q0.x; sy[threadIdx.x] = q0.y; sz[threadIdx.x] = q0.z;
    float px = pos_skip[m * 3 + 0];
    float py = pos_skip[m * 3 + 1];
    float pz = pos_skip[m * 3 + 2];
    __syncthreads();

    float d0 = 1e30f, d1 = 1e30f, d2 = 1e30f;
    int i0 = jbase, i1 = jbase, i2 = jbase;
#pragma unroll 2
    for (int j4 = 0; j4 < CHSZ; j4 += 4) {
        float4 qx = *(const float4*)&sx[j4];
        float4 qy = *(const float4*)&sy[j4];
        float4 qz = *(const float4*)&sz[j4];
#pragma unroll
        for (int u = 0; u < 4; ++u) {
            float dx = px - qx[u], dy = py - qy[u], dz = pz - qz[u];
            float d = dx * dx + dy * dy + dz * dz;
            int jj = jbase + j4 + u;
            TOP3_INSERT(d, jj);
        }
    }
    size_t base = ((size_t)c * MTOT + m) * 3;
    pdst[base + 0] = d0; pdst[base + 1] = d1; pdst[base + 2] = d2;
    pidx[base + 0] = i0; pidx[base + 1] = i1; pidx[base + 2] = i2;
}

// ---- kernel 2b: merge 8 chunk-partials -> final top-3 + weights
__global__ __launch_bounds__(64) void knn_merge(const int* __restrict__ pidx,
                                                const float* __restrict__ pdst,
                                                int* __restrict__ idxw,
                                                float* __restrict__ wgt) {
    int m = blockIdx.x * 64 + threadIdx.x;
    float d0 = 1e30f, d1 = 1e30f, d2 = 1e30f;
    int i0 = 0, i1 = 0, i2 = 0;
#pragma unroll
    for (int c = 0; c < NCHUNK; ++c) {
        size_t base = ((size_t)c * MTOT + m) * 3;
#pragma unroll
        for (int s = 0; s < 3; ++s) {
            float d = pdst[base + s];
            int jj = pidx[base + s];
            TOP3_INSERT(d, jj);
        }
    }
    float w0 = 1.0f / fmaxf(d0, 1e-16f);
    float w1 = 1.0f / fmaxf(d1, 1e-16f);
    float w2 = 1.0f / fmaxf(d2, 1e-16f);
    float inv = 1.0f / (w0 + w1 + w2);
    idxw[m * 3 + 0] = i0;  wgt[m * 3 + 0] = w0 * inv;
    idxw[m * 3 + 1] = i1;  wgt[m * 3 + 1] = w1 * inv;
    idxw[m * 3 + 2] = i2;  wgt[m * 3 + 2] = w2 * inv;
}

// ---- kernel 3: Gb = bf16( xb @ Bt1a^T ). 16384 x 256, K=256.
__global__ __launch_bounds__(256) void gemm_G(const ushort* __restrict__ A,
                                              const ushort* __restrict__ Bt,
                                              ushort* __restrict__ Gb) {
    int wave = threadIdx.x >> 6, lane = threadIdx.x & 63;
    int m0 = blockIdx.x * 16;
    int lrow = lane & 15;
    int ko = (lane >> 4) * 8;
    const ushort* arow = A + (size_t)(m0 + lrow) * 256 + ko;
    const ushort* bbase = Bt + (size_t)(wave * 64 + lrow) * 256 + ko;

    floatx4 acc[4];
#pragma unroll
    for (int i = 0; i < 4; ++i) acc[i] = (floatx4){0.f, 0.f, 0.f, 0.f};

    for (int k0 = 0; k0 < 256; k0 += 32) {
        short8 af = *(const short8*)(arow + k0);
#pragma unroll
        for (int nt = 0; nt < 4; ++nt) {
            short8 bf = *(const short8*)(bbase + (size_t)nt * 16 * 256 + k0);
            acc[nt] = __builtin_amdgcn_mfma_f32_16x16x32_bf16(af, bf, acc[nt], 0, 0, 0);
        }
    }
    int rbase = (lane >> 4) * 4;
#pragma unroll
    for (int nt = 0; nt < 4; ++nt) {
        int n = wave * 64 + nt * 16 + lrow;
#pragma unroll
        for (int r = 0; r < 4; ++r)
            Gb[(size_t)(m0 + rbase + r) * 256 + n] = f2bf(acc[nt][r]);
    }
}

// ---- kernel 4: fused  h1 = relu(x_skip@W1b + interp(Gb) + b1);  out = relu(h1@W2 + b2)
// Round-5 lesson: per-wave global B reads = 160 KB/wave of L2 round-trips with
// a working set L1 can't hold -> latency-bound at 132us with all pipes <10%.
// Fix: block-shared LDS staging of B (m97 pattern). Bt1b staged once (36 KB
// padded); Bt2 staged in four 64-wide k-slices reusing the same buffer.
// Row stride 72 ushorts = 144 B: 16B-aligned for ds_read_b128, worst 2-way
// bank aliasing (free per m136).
#define LDS_STRIDE 264
#define WB_STRIDE 72
__global__ __launch_bounds__(256) void fused_kernel(const ushort* __restrict__ xsb,
                                                    const ushort* __restrict__ Bt1b,
                                                    const ushort* __restrict__ Gb,
                                                    const int* __restrict__ idxw,
                                                    const float* __restrict__ wgt,
                                                    const float* __restrict__ b1,
                                                    const ushort* __restrict__ Bt2,
                                                    const float* __restrict__ b2,
                                                    float* __restrict__ out) {
    __shared__ ushort h1t[4][16 * LDS_STRIDE];     // 33792 B
    __shared__ ushort wB[256 * WB_STRIDE];         // 36864 B
    __shared__ int   sIdx[4][48];
    __shared__ float sWgt[4][48];                  // 1536 B  (total ~72 KB -> 2 blk/CU)
    int tid = threadIdx.x;
    int wave = tid >> 6, lane = tid & 63;
    int m0 = blockIdx.x * 64 + wave * 16;
    int lrow = lane & 15;
    int ko = (lane >> 4) * 8;
    int rbase = (lane >> 4) * 4;

    // ---- phase 0: idx/wgt -> wave-private LDS via the vector path (round-4 lesson)
    if (lane < 48) {
        sIdx[wave][lane] = idxw[m0 * 3 + lane];
        sWgt[wave][lane] = wgt[m0 * 3 + lane];
    }

    const ushort4* Gv = (const ushort4*)Gb;
    const int*   si = sIdx[wave];
    const float* sw = sWgt[wave];
    ushort4 g[4][3];
#define GATHER(slot, i) {                                         \
        int a0 = si[(i) * 3 + 0];                                 \
        int a1 = si[(i) * 3 + 1];                                 \
        int a2 = si[(i) * 3 + 2];                                 \
        g[slot][0] = Gv[(size_t)a0 * 64 + lane];                  \
        g[slot][1] = Gv[(size_t)a1 * 64 + lane];                  \
        g[slot][2] = Gv[(size_t)a2 * 64 + lane]; }

    // issue first 4 gather batches early: latency hides under staging + stage 1
    GATHER(0, 0) GATHER(1, 1) GATHER(2, 2) GATHER(3, 3)

    // ---- stage Bt1b (256 x 64) into wB
    for (int cch = tid; cch < 2048; cch += 256) {
        int n = cch >> 3, koff = (cch & 7) * 8;
        *(short8*)&wB[n * WB_STRIDE + koff] = *(const short8*)(Bt1b + n * 64 + koff);
    }
    __syncthreads();

    // ---- stage 1: S = x_skip_tile @ W1b^T  (K=64), B from LDS
    floatx4 acc[16];
#pragma unroll
    for (int i = 0; i < 16; ++i) acc[i] = (floatx4){0.f, 0.f, 0.f, 0.f};
    {
        const ushort* arow = xsb + (size_t)(m0 + lrow) * 64 + ko;
#pragma unroll
        for (int k0 = 0; k0 < 64; k0 += 32) {
            short8 af = *(const short8*)(arow + k0);
#pragma unroll
            for (int nt = 0; nt < 16; ++nt) {
                short8 bf = *(const short8*)&wB[(nt * 16 + lrow) * WB_STRIDE + k0 + ko];
                acc[nt] = __builtin_amdgcn_mfma_f32_16x16x32_bf16(af, bf, acc[nt], 0, 0, 0);
            }
        }
    }

    // ---- stage 2a: S (bf16) -> wave-private LDS tile at C-layout positions
    ushort* ht = h1t[wave];
#pragma unroll
    for (int nt = 0; nt < 16; ++nt) {
        int n = nt * 16 + lrow;
#pragma unroll
        for (int r = 0; r < 4; ++r)
            ht[(rbase + r) * LDS_STRIDE + n] = f2bf(acc[nt][r]);
    }

    // ---- stage 2b: cooperative interp (lane owns cols 4L..4L+3), depth-4 pipeline
    {
        float4 bv = ((const float4*)b1)[lane];
#define COMBINE(i) {                                              \
        int s = (i) & 3;                                          \
        float w0 = sw[(i) * 3 + 0], w1 = sw[(i) * 3 + 1], w2 = sw[(i) * 3 + 2]; \
        ushort4 sv = *(const ushort4*)(ht + (i) * LDS_STRIDE + 4 * lane); \
        float4 h;                                                 \
        h.x = fmaxf(bf2f(sv.x) + w0 * bf2f(g[s][0].x) + w1 * bf2f(g[s][1].x) + w2 * bf2f(g[s][2].x) + bv.x, 0.f); \
        h.y = fmaxf(bf2f(sv.y) + w0 * bf2f(g[s][0].y) + w1 * bf2f(g[s][1].y) + w2 * bf2f(g[s][2].y) + bv.y, 0.f); \
        h.z = fmaxf(bf2f(sv.z) + w0 * bf2f(g[s][0].z) + w1 * bf2f(g[s][1].z) + w2 * bf2f(g[s][2].z) + bv.z, 0.f); \
        h.w = fmaxf(bf2f(sv.w) + w0 * bf2f(g[s][0].w) + w1 * bf2f(g[s][1].w) + w2 * bf2f(g[s][2].w) + bv.w, 0.f); \
        ushort4 hp;                                               \
        hp.x = f2bf(h.x); hp.y = f2bf(h.y); hp.z = f2bf(h.z); hp.w = f2bf(h.w); \
        *(ushort4*)(ht + (i) * LDS_STRIDE + 4 * lane) = hp; }

#pragma unroll
        for (int i = 0; i < 12; ++i) { COMBINE(i); GATHER(i & 3, i + 4); }
#pragma unroll
        for (int i = 12; i < 16; ++i) { COMBINE(i); }
#undef GATHER
#undef COMBINE
    }

    // ---- stage 3: out = relu(h1 @ W2^T + b2), K=256 in four 64-wide slices;
    // Bt2 slice staged in wB (shared), A from own h1t tile.
#pragma unroll
    for (int i = 0; i < 16; ++i) acc[i] = (floatx4){0.f, 0.f, 0.f, 0.f};
    for (int s = 0; s < 4; ++s) {
        __syncthreads();                               // wB free (prev users done)
        for (int cch = tid; cch < 2048; cch += 256) {
            int n = cch >> 3, koff = (cch & 7) * 8;
            *(short8*)&wB[n * WB_STRIDE + koff] = *(const short8*)(Bt2 + n * 256 + s * 64 + koff);
        }
        __syncthreads();
        const ushort* ar = ht + lrow * LDS_STRIDE + s * 64 + ko;
#pragma unroll
        for (int k0 = 0; k0 < 64; k0 += 32) {
            short8 af = *(const short8*)(ar + k0);
#pragma unroll
            for (int nt = 0; nt < 16; ++nt) {
                short8 bf = *(const short8*)&wB[(nt * 16 + lrow) * WB_STRIDE + k0 + ko];
                acc[nt] = __builtin_amdgcn_mfma_f32_16x16x32_bf16(af, bf, acc[nt], 0, 0, 0);
            }
        }
    }
#pragma unroll
    for (int nt = 0; nt < 16; ++nt) {
        int n = nt * 16 + lrow;
        float bv2 = b2[n];
#pragma unroll
        for (int r = 0; r < 4; ++r) {
            float v = fmaxf(acc[nt][r] + bv2, 0.f);
            out[(size_t)(m0 + rbase + r) * OUTD + n] = v;
        }
    }
}

extern "C" void kernel_launch(void* const* d_in, const int* in_sizes, int n_in,
                              void* d_out, int out_size, void* d_ws, size_t ws_size,
                              hipStream_t stream) {
    const float* x        = (const float*)d_in[0];
    const float* pos      = (const float*)d_in[1];
    const float* x_skip   = (const float*)d_in[3];
    const float* pos_skip = (const float*)d_in[4];
    const float* W1       = (const float*)d_in[6];
    const float* b1       = (const float*)d_in[7];
    const float* W2       = (const float*)d_in[8];
    const float* b2       = (const float*)d_in[9];

    char* ws = (char*)d_ws;
    size_t off = 0;
    int*    idxw = (int*)(ws + off);    off += (size_t)MTOT * 3 * 4;      //  768 KB
    float*  wgt  = (float*)(ws + off);  off += (size_t)MTOT * 3 * 4;      //  768 KB
    ushort* xb   = (ushort*)(ws + off); off += (size_t)NCTOT * 256 * 2;   //    8 MB
    ushort* xsb  = (ushort*)(ws + off); off += (size_t)MTOT * 64 * 2;     //    8 MB
    ushort* Gb   = (ushort*)(ws + off); off += (size_t)NCTOT * 256 * 2;   //    8 MB
    ushort* Bt1a = (ushort*)(ws + off); off += (size_t)256 * 256 * 2;     //  128 KB
    ushort* Bt1b = (ushort*)(ws + off); off += (size_t)256 * 64 * 2;      //   32 KB
    ushort* Bt2  = (ushort*)(ws + off); off += (size_t)256 * 256 * 2;     //  128 KB
    float4* pos4 = (float4*)(ws + off); off += (size_t)(NCTOT + 4) * 16;  //  256 KB
    // total ~26 MB (inside proven budget). kNN chunk partials live in
    // d_out[0:12.6MB]: dead before fused_kernel overwrites that region.
    float* out = (float*)d_out;
    int*   pidx = (int*)d_out;
    float* pdst = (float*)((char*)d_out + (size_t)NCHUNK * MTOT * 3 * 4);

    prep_kernel<<<(PREP_THREADS + 255) / 256, 256, 0, stream>>>(
        x, x_skip, W1, W2, pos, pos_skip, xb, xsb, Bt1a, Bt1b, Bt2, pos4, out);
    knn_part<<<(MTOT / 256) * NCHUNK, 256, 0, stream>>>(pos4, pos_skip, pidx, pdst);
    knn_merge<<<MTOT / 64, 64, 0, stream>>>(pidx, pdst, idxw, wgt);
    gemm_G<<<NCTOT / 16, 256, 0, stream>>>(xb, Bt1a, Gb);
    fused_kernel<<<MTOT / 64, 256, 0, stream>>>(xsb, Bt1b, Gb, idxw, wgt, b1, Bt2, b2, out);
}

// Round 7
// 226.200 us; speedup vs baseline: 2.8585x; 1.0137x over previous
//
#include <hip/hip_runtime.h>
#include <hip/hip_bf16.h>

#define BATCH 8
#define NC 2048
#define NF 8192
#define CDIM 256
#define CSKIP 64
#define OUTD 256
#define MTOT (BATCH*NF)   // 65536
#define NCTOT (BATCH*NC)  // 16384
#define NCHUNK 8          // kNN coarse-scan split
#define CHSZ (NC/NCHUNK)  // 256

typedef __attribute__((ext_vector_type(8))) short short8;
typedef __attribute__((ext_vector_type(4))) float floatx4;

static __device__ __forceinline__ ushort f2bf(float f) {
    union { float f; unsigned u; } v; v.f = f;
    unsigned r = v.u + 0x7fffu + ((v.u >> 16) & 1u);   // RNE
    return (ushort)(r >> 16);
}
static __device__ __forceinline__ float bf2f(ushort u) {
    union { unsigned u; float f; } v; v.u = ((unsigned)u) << 16;
    return v.f;
}

#if defined(__has_builtin) && __has_builtin(__builtin_amdgcn_fmed3f)
#define MED3F(a, b, c) __builtin_amdgcn_fmed3f((a), (b), (c))
#else
static __device__ __forceinline__ float MED3F(float a, float b, float c) {
    return fmaxf(fminf(a, b), fminf(fmaxf(a, b), c));
}
#endif

// branchless strict-< top-3 insert, parametrized state (exact jax top_k tie order
// when fed ascending j)
#define TOP3_INS(d, jj, D0, D1, D2, I0, I1, I2)     \
    {                                               \
        bool c2 = (d) < D2, c1 = (d) < D1, c0 = (d) < D0; \
        I2 = c1 ? I1 : (c2 ? (jj) : I2);            \
        I1 = c0 ? I0 : (c1 ? (jj) : I1);            \
        I0 = c0 ? (jj) : I0;                        \
        D2 = MED3F(D1, D2, (d));                    \
        D1 = MED3F(D0, D1, (d));                    \
        D0 = fminf(D0, (d));                        \
    }

// ---- kernel 1: prep (bf16 casts of x / x_skip, pos padding, tail outputs)
#define SEG0 1048576   // x -> xb bf16 (float4-wide)
#define SEG1 1048576   // x_skip -> xsb bf16
#define SEG5 16384     // pos -> pos4
#define SEG6 (MTOT*3)  // pos_skip -> out tail
#define SEG7 MTOT      // batch ids -> out tail
#define PREP_THREADS (SEG0+SEG1+SEG5+SEG6+SEG7)

__global__ __launch_bounds__(256) void prep_kernel(const float* __restrict__ x,
                                                   const float* __restrict__ x_skip,
                                                   const float* __restrict__ pos,
                                                   const float* __restrict__ pos_skip,
                                                   ushort* __restrict__ xb,
                                                   ushort* __restrict__ xsb,
                                                   float4* __restrict__ pos4,
                                                   float* __restrict__ out) {
    int t = blockIdx.x * 256 + threadIdx.x;
    if (t < SEG0) {
        float4 v = ((const float4*)x)[t];
        ushort4 p; p.x = f2bf(v.x); p.y = f2bf(v.y); p.z = f2bf(v.z); p.w = f2bf(v.w);
        ((ushort4*)xb)[t] = p;
        return;
    }
    t -= SEG0;
    if (t < SEG1) {
        float4 v = ((const float4*)x_skip)[t];
        ushort4 p; p.x = f2bf(v.x); p.y = f2bf(v.y); p.z = f2bf(v.z); p.w = f2bf(v.w);
        ((ushort4*)xsb)[t] = p;
        return;
    }
    t -= SEG1;
    if (t < SEG5) {
        float4 q;
        q.x = pos[t * 3 + 0]; q.y = pos[t * 3 + 1]; q.z = pos[t * 3 + 2]; q.w = 0.f;
        pos4[t] = q;
        return;
    }
    t -= SEG5;
    if (t < SEG6) {
        out[(size_t)MTOT * OUTD + t] = pos_skip[t];
        return;
    }
    t -= SEG6;
    if (t < SEG7) {
        out[(size_t)MTOT * OUTD + (size_t)MTOT * 3 + t] = (float)(t >> 13);
    }
}

// ---- kernel 1b: LDS-tiled weight transpose (coalesced read AND write).
// blocks 0..15: W1[0:256,:] -> Bt1a ; 16..19: W1[256:320,:] -> Bt1b ;
// 20..35: W2 -> Bt2.  64x64 tiles, pad 65 breaks bank conflicts.
__global__ __launch_bounds__(256) void prep_w(const float* __restrict__ W1,
                                              const float* __restrict__ W2,
                                              ushort* __restrict__ Bt1a,
                                              ushort* __restrict__ Bt1b,
                                              ushort* __restrict__ Bt2) {
    __shared__ ushort tile[64 * 65];
    int bid = blockIdx.x;
    const float* src; ushort* dst; int k0, n0, KD;
    if (bid < 16)      { src = W1;             dst = Bt1a; k0 = (bid >> 2) * 64; n0 = (bid & 3) * 64; KD = 256; }
    else if (bid < 20) { src = W1 + 256 * 256; dst = Bt1b; k0 = 0;               n0 = (bid - 16) * 64; KD = 64; }
    else               { int b2 = bid - 20; src = W2; dst = Bt2; k0 = (b2 >> 2) * 64; n0 = (b2 & 3) * 64; KD = 256; }
    int tx = threadIdx.x & 63, ty = threadIdx.x >> 6;
#pragma unroll
    for (int r = 0; r < 64; r += 4) {
        int k = r + ty;
        tile[k * 65 + tx] = f2bf(src[(size_t)(k0 + k) * 256 + n0 + tx]);
    }
    __syncthreads();
#pragma unroll
    for (int r = 0; r < 64; r += 4) {
        int n = r + ty;
        dst[(size_t)(n0 + n) * KD + k0 + tx] = tile[tx * 65 + n];
    }
}

// ---- kernel 2a: chunked kNN partials, 2 fine points per thread.
// SoA coarse chunk in LDS; LDS reads + loop/addr overhead amortized over 2 pts.
__global__ __launch_bounds__(256) void knn_part(const float4* __restrict__ pos4,
                                                const float* __restrict__ pos_skip,
                                                int* __restrict__ pidx,
                                                float* __restrict__ pdst) {
    __shared__ float sx[CHSZ], sy[CHSZ], sz[CHSZ];     // 3 KB
    int c = blockIdx.x & (NCHUNK - 1);
    int mA = (blockIdx.x >> 3) * 512 + threadIdx.x;
    int mB = mA + 256;
    int b = mA >> 13;                                  // both pts in same cloud
    int jbase = b * NC + c * CHSZ;

    float4 q0 = pos4[jbase + threadIdx.x];
    sx[threadIdx.x] = q0.x; sy[threadIdx.x] = q0.y; sz[threadIdx.x] = q0.z;
    float pxA = pos_skip[mA * 3 + 0];
    float pyA = pos_skip[mA * 3 + 1];
    float pzA = pos_skip[mA * 3 + 2];
    float pxB = pos_skip[mB * 3 + 0];
    float pyB = pos_skip[mB * 3 + 1];
    float pzB = pos_skip[mB * 3 + 2];
    __syncthreads();

    float dA0 = 1e30f, dA1 = 1e30f, dA2 = 1e30f;
    float dB0 = 1e30f, dB1 = 1e30f, dB2 = 1e30f;
    int iA0 = jbase, iA1 = jbase, iA2 = jbase;
    int iB0 = jbase, iB1 = jbase, iB2 = jbase;
#pragma unroll 2
    for (int j4 = 0; j4 < CHSZ; j4 += 4) {
        float4 qx = *(const float4*)&sx[j4];
        float4 qy = *(const float4*)&sy[j4];
        float4 qz = *(const float4*)&sz[j4];
#pragma unroll
        for (int u = 0; u < 4; ++u) {
            int jj = jbase + j4 + u;
            float ax = pxA - qx[u], ay = pyA - qy[u], az = pzA - qz[u];
            float dA = ax * ax + ay * ay + az * az;
            TOP3_INS(dA, jj, dA0, dA1, dA2, iA0, iA1, iA2);
            float bx = pxB - qx[u], by = pyB - qy[u], bz = pzB - qz[u];
            float dB = bx * bx + by * by + bz * bz;
            TOP3_INS(dB, jj, dB0, dB1, dB2, iB0, iB1, iB2);
        }
    }
    size_t baseA = ((size_t)c * MTOT + mA) * 3;
    pdst[baseA + 0] = dA0; pdst[baseA + 1] = dA1; pdst[baseA + 2] = dA2;
    pidx[baseA + 0] = iA0; pidx[baseA + 1] = iA1; pidx[baseA + 2] = iA2;
    size_t baseB = ((size_t)c * MTOT + mB) * 3;
    pdst[baseB + 0] = dB0; pdst[baseB + 1] = dB1; pdst[baseB + 2] = dB2;
    pidx[baseB + 0] = iB0; pidx[baseB + 1] = iB1; pidx[baseB + 2] = iB2;
}

// ---- kernel 2b: merge 8 chunk-partials -> final top-3 + weights
__global__ __launch_bounds__(64) void knn_merge(const int* __restrict__ pidx,
                                                const float* __restrict__ pdst,
                                                int* __restrict__ idxw,
                                                float* __restrict__ wgt) {
    int m = blockIdx.x * 64 + threadIdx.x;
    float d0 = 1e30f, d1 = 1e30f, d2 = 1e30f;
    int i0 = 0, i1 = 0, i2 = 0;
#pragma unroll
    for (int c = 0; c < NCHUNK; ++c) {
        size_t base = ((size_t)c * MTOT + m) * 3;
#pragma unroll
        for (int s = 0; s < 3; ++s) {
            float d = pdst[base + s];
            int jj = pidx[base + s];
            TOP3_INS(d, jj, d0, d1, d2, i0, i1, i2);
        }
    }
    float w0 = 1.0f / fmaxf(d0, 1e-16f);
    float w1 = 1.0f / fmaxf(d1, 1e-16f);
    float w2 = 1.0f / fmaxf(d2, 1e-16f);
    float inv = 1.0f / (w0 + w1 + w2);
    idxw[m * 3 + 0] = i0;  wgt[m * 3 + 0] = w0 * inv;
    idxw[m * 3 + 1] = i1;  wgt[m * 3 + 1] = w1 * inv;
    idxw[m * 3 + 2] = i2;  wgt[m * 3 + 2] = w2 * inv;
}

// ---- kernel 3: Gb = bf16( xb @ Bt1a^T ). 16384 x 256, K=256.
// Round-6 lesson applied here too: B staged in block-shared LDS k-slices
// (round-5-style per-wave global B reads were the fused 132us disease).
#define GW_STRIDE 72
__global__ __launch_bounds__(256) void gemm_G(const ushort* __restrict__ A,
                                              const ushort* __restrict__ Bt,
                                              ushort* __restrict__ Gb) {
    __shared__ ushort wB[256 * GW_STRIDE];             // 36 KB
    int tid = threadIdx.x;
    int wave = tid >> 6, lane = tid & 63;
    int m0 = blockIdx.x * 64 + wave * 16;
    int lrow = lane & 15;
    int ko = (lane >> 4) * 8;

    floatx4 acc[16];
#pragma unroll
    for (int i = 0; i < 16; ++i) acc[i] = (floatx4){0.f, 0.f, 0.f, 0.f};

    for (int s = 0; s < 4; ++s) {
        if (s) __syncthreads();
        for (int cch = tid; cch < 2048; cch += 256) {
            int n = cch >> 3, koff = (cch & 7) * 8;
            *(short8*)&wB[n * GW_STRIDE + koff] = *(const short8*)(Bt + n * 256 + s * 64 + koff);
        }
        __syncthreads();
        const ushort* ar = A + (size_t)(m0 + lrow) * 256 + s * 64 + ko;
#pragma unroll
        for (int k0 = 0; k0 < 64; k0 += 32) {
            short8 af = *(const short8*)(ar + k0);
#pragma unroll
            for (int nt = 0; nt < 16; ++nt) {
                short8 bf = *(const short8*)&wB[(nt * 16 + lrow) * GW_STRIDE + k0 + ko];
                acc[nt] = __builtin_amdgcn_mfma_f32_16x16x32_bf16(af, bf, acc[nt], 0, 0, 0);
            }
        }
    }
    int rbase = (lane >> 4) * 4;
#pragma unroll
    for (int nt = 0; nt < 16; ++nt) {
        int n = nt * 16 + lrow;
#pragma unroll
        for (int r = 0; r < 4; ++r)
            Gb[(size_t)(m0 + rbase + r) * 256 + n] = f2bf(acc[nt][r]);
    }
}

// ---- kernel 4: fused  h1 = relu(x_skip@W1b + interp(Gb) + b1);  out = relu(h1@W2 + b2)
// (round-6 structure: block-shared LDS B, idx/wgt via vector path, pipelined gathers)
#define LDS_STRIDE 264
#define WB_STRIDE 72
__global__ __launch_bounds__(256) void fused_kernel(const ushort* __restrict__ xsb,
                                                    const ushort* __restrict__ Bt1b,
                                                    const ushort* __restrict__ Gb,
                                                    const int* __restrict__ idxw,
                                                    const float* __restrict__ wgt,
                                                    const float* __restrict__ b1,
                                                    const ushort* __restrict__ Bt2,
                                                    const float* __restrict__ b2,
                                                    float* __restrict__ out) {
    __shared__ ushort h1t[4][16 * LDS_STRIDE];     // 33792 B
    __shared__ ushort wB[256 * WB_STRIDE];         // 36864 B
    __shared__ int   sIdx[4][48];
    __shared__ float sWgt[4][48];                  // total ~72 KB -> 2 blk/CU
    int tid = threadIdx.x;
    int wave = tid >> 6, lane = tid & 63;
    int m0 = blockIdx.x * 64 + wave * 16;
    int lrow = lane & 15;
    int ko = (lane >> 4) * 8;
    int rbase = (lane >> 4) * 4;

    if (lane < 48) {
        sIdx[wave][lane] = idxw[m0 * 3 + lane];
        sWgt[wave][lane] = wgt[m0 * 3 + lane];
    }

    const ushort4* Gv = (const ushort4*)Gb;
    const int*   si = sIdx[wave];
    const float* sw = sWgt[wave];
    ushort4 g[4][3];
#define GATHER(slot, i) {                                         \
        int a0 = si[(i) * 3 + 0];                                 \
        int a1 = si[(i) * 3 + 1];                                 \
        int a2 = si[(i) * 3 + 2];                                 \
        g[slot][0] = Gv[(size_t)a0 * 64 + lane];                  \
        g[slot][1] = Gv[(size_t)a1 * 64 + lane];                  \
        g[slot][2] = Gv[(size_t)a2 * 64 + lane]; }

    GATHER(0, 0) GATHER(1, 1) GATHER(2, 2) GATHER(3, 3)

    for (int cch = tid; cch < 2048; cch += 256) {
        int n = cch >> 3, koff = (cch & 7) * 8;
        *(short8*)&wB[n * WB_STRIDE + koff] = *(const short8*)(Bt1b + n * 64 + koff);
    }
    __syncthreads();

    floatx4 acc[16];
#pragma unroll
    for (int i = 0; i < 16; ++i) acc[i] = (floatx4){0.f, 0.f, 0.f, 0.f};
    {
        const ushort* arow = xsb + (size_t)(m0 + lrow) * 64 + ko;
#pragma unroll
        for (int k0 = 0; k0 < 64; k0 += 32) {
            short8 af = *(const short8*)(arow + k0);
#pragma unroll
            for (int nt = 0; nt < 16; ++nt) {
                short8 bf = *(const short8*)&wB[(nt * 16 + lrow) * WB_STRIDE + k0 + ko];
                acc[nt] = __builtin_amdgcn_mfma_f32_16x16x32_bf16(af, bf, acc[nt], 0, 0, 0);
            }
        }
    }

    ushort* ht = h1t[wave];
#pragma unroll
    for (int nt = 0; nt < 16; ++nt) {
        int n = nt * 16 + lrow;
#pragma unroll
        for (int r = 0; r < 4; ++r)
            ht[(rbase + r) * LDS_STRIDE + n] = f2bf(acc[nt][r]);
    }

    {
        float4 bv = ((const float4*)b1)[lane];
#define COMBINE(i) {                                              \
        int s = (i) & 3;                                          \
        float w0 = sw[(i) * 3 + 0], w1 = sw[(i) * 3 + 1], w2 = sw[(i) * 3 + 2]; \
        ushort4 sv = *(const ushort4*)(ht + (i) * LDS_STRIDE + 4 * lane); \
        float4 h;                                                 \
        h.x = fmaxf(bf2f(sv.x) + w0 * bf2f(g[s][0].x) + w1 * bf2f(g[s][1].x) + w2 * bf2f(g[s][2].x) + bv.x, 0.f); \
        h.y = fmaxf(bf2f(sv.y) + w0 * bf2f(g[s][0].y) + w1 * bf2f(g[s][1].y) + w2 * bf2f(g[s][2].y) + bv.y, 0.f); \
        h.z = fmaxf(bf2f(sv.z) + w0 * bf2f(g[s][0].z) + w1 * bf2f(g[s][1].z) + w2 * bf2f(g[s][2].z) + bv.z, 0.f); \
        h.w = fmaxf(bf2f(sv.w) + w0 * bf2f(g[s][0].w) + w1 * bf2f(g[s][1].w) + w2 * bf2f(g[s][2].w) + bv.w, 0.f); \
        ushort4 hp;                                               \
        hp.x = f2bf(h.x); hp.y = f2bf(h.y); hp.z = f2bf(h.z); hp.w = f2bf(h.w); \
        *(ushort4*)(ht + (i) * LDS_STRIDE + 4 * lane) = hp; }

#pragma unroll
        for (int i = 0; i < 12; ++i) { COMBINE(i); GATHER(i & 3, i + 4); }
#pragma unroll
        for (int i = 12; i < 16; ++i) { COMBINE(i); }
#undef GATHER
#undef COMBINE
    }

#pragma unroll
    for (int i = 0; i < 16; ++i) acc[i] = (floatx4){0.f, 0.f, 0.f, 0.f};
    for (int s = 0; s < 4; ++s) {
        __syncthreads();
        for (int cch = tid; cch < 2048; cch += 256) {
            int n = cch >> 3, koff = (cch & 7) * 8;
            *(short8*)&wB[n * WB_STRIDE + koff] = *(const short8*)(Bt2 + n * 256 + s * 64 + koff);
        }
        __syncthreads();
        const ushort* ar = ht + lrow * LDS_STRIDE + s * 64 + ko;
#pragma unroll
        for (int k0 = 0; k0 < 64; k0 += 32) {
            short8 af = *(const short8*)(ar + k0);
#pragma unroll
            for (int nt = 0; nt < 16; ++nt) {
                short8 bf = *(const short8*)&wB[(nt * 16 + lrow) * WB_STRIDE + k0 + ko];
                acc[nt] = __builtin_amdgcn_mfma_f32_16x16x32_bf16(af, bf, acc[nt], 0, 0, 0);
            }
        }
    }
#pragma unroll
    for (int nt = 0; nt < 16; ++nt) {
        int n = nt * 16 + lrow;
        float bv2 = b2[n];
#pragma unroll
        for (int r = 0; r < 4; ++r) {
            float v = fmaxf(acc[nt][r] + bv2, 0.f);
            out[(size_t)(m0 + rbase + r) * OUTD + n] = v;
        }
    }
}

extern "C" void kernel_launch(void* const* d_in, const int* in_sizes, int n_in,
                              void* d_out, int out_size, void* d_ws, size_t ws_size,
                              hipStream_t stream) {
    const float* x        = (const float*)d_in[0];
    const float* pos      = (const float*)d_in[1];
    const float* x_skip   = (const float*)d_in[3];
    const float* pos_skip = (const float*)d_in[4];
    const float* W1       = (const float*)d_in[6];
    const float* b1       = (const float*)d_in[7];
    const float* W2       = (const float*)d_in[8];
    const float* b2       = (const float*)d_in[9];

    char* ws = (char*)d_ws;
    size_t off = 0;
    int*    idxw = (int*)(ws + off);    off += (size_t)MTOT * 3 * 4;      //  768 KB
    float*  wgt  = (float*)(ws + off);  off += (size_t)MTOT * 3 * 4;      //  768 KB
    ushort* xb   = (ushort*)(ws + off); off += (size_t)NCTOT * 256 * 2;   //    8 MB
    ushort* xsb  = (ushort*)(ws + off); off += (size_t)MTOT * 64 * 2;     //    8 MB
    ushort* Gb   = (ushort*)(ws + off); off += (size_t)NCTOT * 256 * 2;   //    8 MB
    ushort* Bt1a = (ushort*)(ws + off); off += (size_t)256 * 256 * 2;     //  128 KB
    ushort* Bt1b = (ushort*)(ws + off); off += (size_t)256 * 64 * 2;      //   32 KB
    ushort* Bt2  = (ushort*)(ws + off); off += (size_t)256 * 256 * 2;     //  128 KB
    float4* pos4 = (float4*)(ws + off); off += (size_t)(NCTOT + 4) * 16;  //  256 KB
    // total ~26 MB (inside proven budget). kNN chunk partials live in
    // d_out[0:12.6MB]: dead before fused_kernel overwrites that region.
    float* out = (float*)d_out;
    int*   pidx = (int*)d_out;
    float* pdst = (float*)((char*)d_out + (size_t)NCHUNK * MTOT * 3 * 4);

    prep_kernel<<<(PREP_THREADS + 255) / 256, 256, 0, stream>>>(
        x, x_skip, pos, pos_skip, xb, xsb, pos4, out);
    prep_w<<<36, 256, 0, stream>>>(W1, W2, Bt1a, Bt1b, Bt2);
    knn_part<<<(MTOT / 512) * NCHUNK, 256, 0, stream>>>(pos4, pos_skip, pidx, pdst);
    knn_merge<<<MTOT / 64, 64, 0, stream>>>(pidx, pdst, idxw, wgt);
    gemm_G<<<NCTOT / 64, 256, 0, stream>>>(xb, Bt1a, Gb);
    fused_kernel<<<MTOT / 64, 256, 0, stream>>>(xsb, Bt1b, Gb, idxw, wgt, b1, Bt2, b2, out);
}